// Round 10
// baseline (796.981 us; speedup 1.0000x reference)
//
#include <hip/hip_runtime.h>
#include <hip/hip_bf16.h>
#include <cstdint>
#include <cstddef>

#define DIMC 1024
#define HEADS 16
#define HD 64
#define DFF 4096
#define BB 4
#define SS 4096
#define NROWS (BB*SS)   // 16384

typedef __bf16 bf16_t;
typedef __bf16 bf16x8 __attribute__((ext_vector_type(8)));
typedef __bf16 bf16x4 __attribute__((ext_vector_type(4)));
typedef float  f32x4  __attribute__((ext_vector_type(4)));

#define GLDS16(gp, lp) \
  __builtin_amdgcn_global_load_lds((const __attribute__((address_space(1))) void*)(gp), \
                                   (__attribute__((address_space(3))) void*)(lp), 16, 0, 0)

#define MFMA16(a, b, c) __builtin_amdgcn_mfma_f32_16x16x32_bf16((a), (b), (c), 0, 0, 0)

// ---------------------------------------------------------------- weight transpose f32[K][N] -> bf16[N][K]
__global__ __launch_bounds__(256) void wtrans(const float* __restrict__ W, bf16_t* __restrict__ Wt,
                                              int K, int N) {
  __shared__ float tile[32][33];
  int c0 = blockIdx.x * 32, r0 = blockIdx.y * 32;
  int tx = threadIdx.x, ty = threadIdx.y;
  #pragma unroll
  for (int i = 0; i < 32; i += 8)
    tile[ty + i][tx] = W[(long)(r0 + ty + i) * N + c0 + tx];
  __syncthreads();
  #pragma unroll
  for (int i = 0; i < 32; i += 8)
    Wt[(long)(c0 + ty + i) * K + r0 + tx] = (bf16_t)tile[tx][ty + i];
}

// ---------------------------------------------------------------- LayerNorm f32 row -> bf16 row
__global__ __launch_bounds__(256) void ln_kernel(const float* __restrict__ in,
                                                 const float* __restrict__ gamma,
                                                 const float* __restrict__ beta,
                                                 bf16_t* __restrict__ out) {
  long r = blockIdx.x;
  int t = threadIdx.x;
  float4 v = ((const float4*)(in + r * DIMC))[t];
  float s  = v.x + v.y + v.z + v.w;
  float sq = v.x * v.x + v.y * v.y + v.z * v.z + v.w * v.w;
  #pragma unroll
  for (int o = 32; o > 0; o >>= 1) { s += __shfl_xor(s, o); sq += __shfl_xor(sq, o); }
  __shared__ float red[8];
  if ((t & 63) == 0) { red[(t >> 6) * 2] = s; red[(t >> 6) * 2 + 1] = sq; }
  __syncthreads();
  s  = red[0] + red[2] + red[4] + red[6];
  sq = red[1] + red[3] + red[5] + red[7];
  float mu  = s * (1.0f / DIMC);
  float var = sq * (1.0f / DIMC) - mu * mu;
  float rs  = 1.0f / sqrtf(var + 1e-5f);
  float4 g  = ((const float4*)gamma)[t];
  float4 bb = ((const float4*)beta)[t];
  bf16x4 o;
  o[0] = (bf16_t)((v.x - mu) * rs * g.x + bb.x);
  o[1] = (bf16_t)((v.y - mu) * rs * g.y + bb.y);
  o[2] = (bf16_t)((v.z - mu) * rs * g.z + bb.z);
  o[3] = (bf16_t)((v.w - mu) * rs * g.w + bb.w);
  ((bf16x4*)(out + r * DIMC))[t] = o;
}

// ---------------------------------------------------------------- 256x256 GEMM, 8 waves, BK=64.
// m201-style schedule: per K-tile 4 C-quadrant phases {reads; s_barrier; setprio+16 MFMA; s_barrier},
// stage burst (8 gload_lds, tile t+2) at PH4 start, ONE counted vmcnt(8) per tile after PH4 MFMA.
// NO sched_barrier(0) anywhere (m141: it defeats the compiler scheduler).
// LDS [op][slot][kh][256][32]; lane-constant XOR swizzle; hoisted base addresses.
template <int MODE>
__global__ __launch_bounds__(512, 2) void gemm256(const bf16_t* __restrict__ A,
                                                  const bf16_t* __restrict__ Bt,
                                                  const float* __restrict__ bias,
                                                  const float* __restrict__ resid,
                                                  void* __restrict__ outp,
                                                  int M, int N, int K) {
  __shared__ bf16_t lds[2][2][2][256][32];   // 128 KiB
  const int tid  = threadIdx.x;
  const int lane = tid & 63;
  const int wr   = (tid >> 6) >> 2;   // 0..1  M-half
  const int wc   = (tid >> 6) & 3;    // 0..3  N-quarter

  // T1: bijective XCD swizzle (all nwg here %8==0) + 8-row x 4-col grouping.
  const int nwg  = gridDim.x * gridDim.y;
  const int bid0 = blockIdx.y * gridDim.x + blockIdx.x;
  const int lg   = (bid0 & 7) * (nwg >> 3) + (bid0 >> 3);
  const int span = (int)gridDim.y << 2;          // gridDim.y * 4  (gridDim.x % 4 == 0)
  const int gidx = lg / span;
  const int rem  = lg - gidx * span;
  const int by_  = rem >> 2;
  const int bx_  = (gidx << 2) + (rem & 3);
  const long arow0 = (long)by_ * 256;
  const long brow0 = (long)bx_ * 256;

  const int fr = lane & 15;
  const int q4 = lane >> 4;

  const int srow = tid >> 2;          // staging row 0..127 (then +128)
  const int sc   = tid & 3;           // staging 16B chunk within k-half
  const int gch  = sc ^ ((srow >> 1) & 3);          // lane-constant source chunk
  const int swzB = (q4 ^ ((fr >> 1) & 3)) * 16;     // lane-constant read swizzle (bytes)

  char* const ldsB  = (char*)&lds[0][0][0][0][0];
  const char* aRead = ldsB +         (wr * 128 + fr) * 64 + swzB;
  const char* bRead = ldsB + 65536 + (wc * 64  + fr) * 64 + swzB;
  char* const dstA  = ldsB + srow * 64 + sc * 16;   // linear, gload_lds-safe
  char* const dstB  = dstA + 65536;

  const long rs128 = 128 * (long)K;
  const bf16_t* gA = A  + (arow0 + srow) * (long)K + gch * 8;
  const bf16_t* gB = Bt + (brow0 + srow) * (long)K + gch * 8;

  f32x4 acc[8][4] = {};
  bf16x8 av[8], b0[4], b1[4];
  const int NT = K >> 6;              // 16 or 64 here (even, >= 4)

#define STAGE_U(U, DS)                                                         \
  {                                                                            \
    constexpr int op_ = (U) & 1, kh_ = (U) >> 1;                               \
    const bf16_t* g_ = (op_ ? gB : gA) + kh_ * 32;                             \
    char* d_ = (op_ ? dstB : dstA) + (DS) * 32768 + kh_ * 16384;               \
    GLDS16(g_, d_);                                                            \
    GLDS16(g_ + rs128, d_ + 8192);                                             \
  }

#define LDA8(S, KS, I) (*(const bf16x8*)(aRead + (S) * 32768 + (KS) * 16384 + (I) * 1024))
#define LDB8(S, KS, J) (*(const bf16x8*)(bRead + (S) * 32768 + (KS) * 16384 + (J) * 1024))

// one C-quadrant: rows I0..I0+3, cols J0..J0+1, K=64 (2 k-slices) => 16 MFMA
#define QUAD(I0, J0, B)                                                   \
  __builtin_amdgcn_s_setprio(1);                                          \
  acc[I0+0][J0+0] = MFMA16(av[0], B[0], acc[I0+0][J0+0]);                 \
  acc[I0+0][J0+0] = MFMA16(av[1], B[1], acc[I0+0][J0+0]);                 \
  acc[I0+0][J0+1] = MFMA16(av[0], B[2], acc[I0+0][J0+1]);                 \
  acc[I0+0][J0+1] = MFMA16(av[1], B[3], acc[I0+0][J0+1]);                 \
  acc[I0+1][J0+0] = MFMA16(av[2], B[0], acc[I0+1][J0+0]);                 \
  acc[I0+1][J0+0] = MFMA16(av[3], B[1], acc[I0+1][J0+0]);                 \
  acc[I0+1][J0+1] = MFMA16(av[2], B[2], acc[I0+1][J0+1]);                 \
  acc[I0+1][J0+1] = MFMA16(av[3], B[3], acc[I0+1][J0+1]);                 \
  acc[I0+2][J0+0] = MFMA16(av[4], B[0], acc[I0+2][J0+0]);                 \
  acc[I0+2][J0+0] = MFMA16(av[5], B[1], acc[I0+2][J0+0]);                 \
  acc[I0+2][J0+1] = MFMA16(av[4], B[2], acc[I0+2][J0+1]);                 \
  acc[I0+2][J0+1] = MFMA16(av[5], B[3], acc[I0+2][J0+1]);                 \
  acc[I0+3][J0+0] = MFMA16(av[6], B[0], acc[I0+3][J0+0]);                 \
  acc[I0+3][J0+0] = MFMA16(av[7], B[1], acc[I0+3][J0+0]);                 \
  acc[I0+3][J0+1] = MFMA16(av[6], B[2], acc[I0+3][J0+1]);                 \
  acc[I0+3][J0+1] = MFMA16(av[7], B[3], acc[I0+3][J0+1]);                 \
  __builtin_amdgcn_s_setprio(0);

// one K-tile: S = slot (literal), STG = stage tile t+2 into slot S, VMD = drain (pre-last tile)
#define TILE_BODY(S, STG, VMD)                                            \
  {                                                                       \
    /* PH1: read A(ih0) + B(jh0) */                                       \
    av[0] = LDA8(S, 0, 0); av[1] = LDA8(S, 1, 0);                         \
    av[2] = LDA8(S, 0, 1); av[3] = LDA8(S, 1, 1);                         \
    av[4] = LDA8(S, 0, 2); av[5] = LDA8(S, 1, 2);                         \
    av[6] = LDA8(S, 0, 3); av[7] = LDA8(S, 1, 3);                         \
    b0[0] = LDB8(S, 0, 0); b0[1] = LDB8(S, 1, 0);                         \
    b0[2] = LDB8(S, 0, 1); b0[3] = LDB8(S, 1, 1);                         \
    __builtin_amdgcn_s_barrier();                                         \
    QUAD(0, 0, b0)                                                        \
    __builtin_amdgcn_s_barrier();                                         \
    /* PH2: read B(jh1) */                                                \
    b1[0] = LDB8(S, 0, 2); b1[1] = LDB8(S, 1, 2);                         \
    b1[2] = LDB8(S, 0, 3); b1[3] = LDB8(S, 1, 3);                         \
    __builtin_amdgcn_s_barrier();                                         \
    QUAD(0, 2, b1)                                                        \
    __builtin_amdgcn_s_barrier();                                         \
    /* PH3: read A(ih1) */                                                \
    av[0] = LDA8(S, 0, 4); av[1] = LDA8(S, 1, 4);                         \
    av[2] = LDA8(S, 0, 5); av[3] = LDA8(S, 1, 5);                         \
    av[4] = LDA8(S, 0, 6); av[5] = LDA8(S, 1, 6);                         \
    av[6] = LDA8(S, 0, 7); av[7] = LDA8(S, 1, 7);                         \
    __builtin_amdgcn_s_barrier();                                         \
    QUAD(4, 0, b0)                                                        \
    __builtin_amdgcn_s_barrier();                                         \
    /* PH4: stage burst (slot S reads all done at PH3 trailing barrier) */\
    asm volatile("" ::: "memory");                                        \
    if (STG) { STAGE_U(0, S) STAGE_U(1, S) STAGE_U(2, S) STAGE_U(3, S) }  \
    __builtin_amdgcn_s_barrier();                                         \
    QUAD(4, 2, b1)                                                        \
    if (STG)      asm volatile("s_waitcnt vmcnt(8)" ::: "memory");        \
    else if (VMD) asm volatile("s_waitcnt vmcnt(0)" ::: "memory");        \
    __builtin_amdgcn_s_barrier();                                         \
  }

  // prologue: stage tile0 -> slot0, tile1 -> slot1; wait tile0 (8 of 16 outstanding)
  STAGE_U(0, 0) STAGE_U(1, 0) STAGE_U(2, 0) STAGE_U(3, 0)
  gA += 64; gB += 64;
  STAGE_U(0, 1) STAGE_U(1, 1) STAGE_U(2, 1) STAGE_U(3, 1)
  gA += 64; gB += 64;
  asm volatile("s_waitcnt vmcnt(8)" ::: "memory");
  __builtin_amdgcn_s_barrier();

  for (int t = 0; t < NT; t += 2) {
    const bool stg0 = (t + 2 < NT);
    TILE_BODY(0, stg0, !stg0)          // tile t   (slot 0); drain when no stage (t+1 is last)
    if (stg0) { gA += 64; gB += 64; }
    const bool stg1 = (t + 3 < NT);
    TILE_BODY(1, stg1, false)          // tile t+1 (slot 1); last tile needs no wait
    if (stg1) { gA += 64; gB += 64; }
  }
#undef TILE_BODY
#undef QUAD
#undef LDA8
#undef LDB8
#undef STAGE_U

  const int rq = q4 * 4;
  #pragma unroll
  for (int i = 0; i < 8; ++i) {
    #pragma unroll
    for (int j = 0; j < 4; ++j) {
      long col = brow0 + wc * 64 + j * 16 + fr;
      float bv = bias[col];
      #pragma unroll
      for (int r = 0; r < 4; ++r) {
        long row = arow0 + wr * 128 + i * 16 + rq + r;
        float v = acc[i][j][r] + bv;
        if (MODE == 0) {
          ((bf16_t*)outp)[row * N + col] = (bf16_t)v;
        } else if (MODE == 1) {
          ((float*)outp)[row * N + col] = v + resid[row * N + col];
        } else {
          float g = 0.5f * v * (1.0f + erff(v * 0.70710678118654752f));
          ((bf16_t*)outp)[row * N + col] = (bf16_t)g;
        }
      }
    }
  }
}

// ---------------------------------------------------------------- q softmax (in-place, per (row, head) over 64)
__global__ __launch_bounds__(256) void qsoftmax(bf16_t* __restrict__ qkv) {
  long r = blockIdx.x;
  int t = threadIdx.x, h = t >> 4, l = t & 15;
  bf16_t* p = qkv + r * 3072 + h * 64 + l * 4;
  bf16x4 v4 = *(const bf16x4*)p;
  float v0 = v4[0], v1 = v4[1], v2 = v4[2], v3 = v4[3];
  float m = fmaxf(fmaxf(v0, v1), fmaxf(v2, v3));
  #pragma unroll
  for (int o = 8; o >= 1; o >>= 1) m = fmaxf(m, __shfl_xor(m, o));
  float e0 = __expf(v0 - m), e1 = __expf(v1 - m), e2 = __expf(v2 - m), e3 = __expf(v3 - m);
  float s = e0 + e1 + e2 + e3;
  #pragma unroll
  for (int o = 8; o >= 1; o >>= 1) s += __shfl_xor(s, o);
  float inv = 1.0f / s;
  bf16x4 o4;
  o4[0] = (bf16_t)(e0 * inv); o4[1] = (bf16_t)(e1 * inv);
  o4[2] = (bf16_t)(e2 * inv); o4[3] = (bf16_t)(e3 * inv);
  *(bf16x4*)p = o4;
}

// ---------------------------------------------------------------- k column-softmax stats (online max/sum partials)
__global__ __launch_bounds__(256) void kstats_partial(const bf16_t* __restrict__ qkv,
                                                      float2* __restrict__ part) {
  int bh = blockIdx.x, ch = blockIdx.y;
  int b = bh >> 4, h = bh & 15;
  int t = threadIdx.x, d = t & 63, sr = t >> 6;
  const bf16_t* kp = qkv + (long)b * SS * 3072 + 1024 + h * 64 + d;
  float m = -INFINITY, sum = 0.f;
  for (int s = ch * 512 + sr; s < ch * 512 + 512; s += 4) {
    float v = (float)kp[(long)s * 3072];
    float nm = fmaxf(m, v);
    sum = sum * __expf(m - nm) + __expf(v - nm);
    m = nm;
  }
  __shared__ float2 red[4][64];
  red[sr][d] = make_float2(m, sum);
  __syncthreads();
  if (t < 64) {
    float2 a = red[0][t];
    #pragma unroll
    for (int i = 1; i < 4; ++i) {
      float2 p = red[i][t];
      float nm = fmaxf(a.x, p.x);
      a.y = a.y * __expf(a.x - nm) + p.y * __expf(p.x - nm);
      a.x = nm;
    }
    part[(long)(bh * 8 + ch) * 64 + t] = a;
  }
}

__global__ void kstats_merge(const float2* __restrict__ part, float2* __restrict__ stat) {
  int bh = blockIdx.x, d = threadIdx.x;  // 64 threads
  float m = -INFINITY, s = 0.f;
  #pragma unroll
  for (int c = 0; c < 8; ++c) {
    float2 p = part[(long)(bh * 8 + c) * 64 + d];
    float nm = fmaxf(m, p.x);
    s = s * __expf(m - nm) + p.y * __expf(p.x - nm);
    m = nm;
  }
  stat[bh * 64 + d] = make_float2(m, 1.0f / s);
}

// ---------------------------------------------------------------- kv = sum_s softmax_k[s,d] * v[s,e]  (partials over s-chunks)
__global__ __launch_bounds__(256) void kv_partial(const bf16_t* __restrict__ qkv,
                                                  const float2* __restrict__ stat,
                                                  float* __restrict__ kvp) {
  int bh = blockIdx.x, ch = blockIdx.y;
  int b = bh >> 4, h = bh & 15;
  int t = threadIdx.x;
  __shared__ float  Kexp[64][65];
  __shared__ bf16_t Vs[64][72];
  __shared__ float  kmaxs[64], kinvs[64];
  if (t < 64) { float2 p = stat[bh * 64 + t]; kmaxs[t] = p.x; kinvs[t] = p.y; }
  int rowl = t >> 2, c0 = (t & 3) * 16;
  int dd = t >> 2, e0 = (t & 3) * 16;
  float acc[16] = {};
  for (int sb = 0; sb < 8; ++sb) {
    long s = (long)ch * 512 + sb * 64 + rowl;
    const bf16_t* base = qkv + ((long)b * SS + s) * 3072 + h * 64;
    bf16x8 k0 = *(const bf16x8*)(base + 1024 + c0);
    bf16x8 k1 = *(const bf16x8*)(base + 1024 + c0 + 8);
    bf16x8 v0 = *(const bf16x8*)(base + 2048 + c0);
    bf16x8 v1 = *(const bf16x8*)(base + 2048 + c0 + 8);
    __syncthreads();
    #pragma unroll
    for (int j = 0; j < 8; ++j) {
      Kexp[rowl][c0 + j]     = __expf((float)k0[j] - kmaxs[c0 + j]) * kinvs[c0 + j];
      Kexp[rowl][c0 + 8 + j] = __expf((float)k1[j] - kmaxs[c0 + 8 + j]) * kinvs[c0 + 8 + j];
    }
    *(bf16x8*)&Vs[rowl][c0]     = v0;
    *(bf16x8*)&Vs[rowl][c0 + 8] = v1;
    __syncthreads();
    for (int ls = 0; ls < 64; ++ls) {
      float kd = Kexp[ls][dd];
      bf16x8 va = *(const bf16x8*)&Vs[ls][e0];
      bf16x8 vb = *(const bf16x8*)&Vs[ls][e0 + 8];
      #pragma unroll
      for (int j = 0; j < 8; ++j) {
        acc[j]     += kd * (float)va[j];
        acc[j + 8] += kd * (float)vb[j];
      }
    }
  }
  float* dst = kvp + (long)(bh * 8 + ch) * 4096 + dd * 64 + e0;
  #pragma unroll
  for (int j = 0; j < 16; ++j) dst[j] = acc[j];
}

// reduce partials, store TRANSPOSED bf16: kvT[bh][e][d]
__global__ void kv_reduce(const float* __restrict__ kvp, bf16_t* __restrict__ kvT) {
  int bh = blockIdx.x, t = threadIdx.x;
  for (int p = t; p < 4096; p += 256) {
    int d = p >> 6, e = p & 63;
    float s = 0.f;
    #pragma unroll
    for (int c = 0; c < 8; ++c) s += kvp[(long)(bh * 8 + c) * 4096 + p];
    kvT[(long)bh * 4096 + e * 64 + d] = (bf16_t)s;
  }
}

// ---------------------------------------------------------------- out[s,e] = q_sm[s,:] @ kv[:,e]  via MFMA, per (b,h)
__global__ __launch_bounds__(256) void attn_apply(const bf16_t* __restrict__ qkv,
                                                  const bf16_t* __restrict__ kvT,
                                                  bf16_t* __restrict__ attn) {
  int bh = blockIdx.x, sc = blockIdx.y;
  int b = bh >> 4, h = bh & 15;
  int t = threadIdx.x, lane = t & 63, w = t >> 6;
  __shared__ bf16_t kvs[64 * 64];
  for (int i = t * 8; i < 4096; i += 256 * 8)
    *(bf16x8*)&kvs[i] = *(const bf16x8*)(kvT + (long)bh * 4096 + i);
  __syncthreads();
  int fr = lane & 15, kq = (lane >> 4) * 8;
  long qrow = (long)b * SS + sc * 128 + w * 32;
  f32x4 acc[2][4] = {};
  #pragma unroll
  for (int kk = 0; kk < 2; ++kk) {
    bf16x8 a0 = *(const bf16x8*)(qkv + (qrow + fr) * 3072      + h * 64 + kk * 32 + kq);
    bf16x8 a1 = *(const bf16x8*)(qkv + (qrow + 16 + fr) * 3072 + h * 64 + kk * 32 + kq);
    #pragma unroll
    for (int j = 0; j < 4; ++j) {
      bf16x8 bfr = *(const bf16x8*)&kvs[(j * 16 + fr) * 64 + kk * 32 + kq];
      acc[0][j] = MFMA16(a0, bfr, acc[0][j]);
      acc[1][j] = MFMA16(a1, bfr, acc[1][j]);
    }
  }
  int rq = (lane >> 4) * 4;
  #pragma unroll
  for (int i = 0; i < 2; ++i)
    #pragma unroll
    for (int j = 0; j < 4; ++j)
      #pragma unroll
      for (int r = 0; r < 4; ++r)
        attn[(qrow + i * 16 + rq + r) * 1024 + h * 64 + j * 16 + fr] = (bf16_t)acc[i][j][r];
}

// ---------------------------------------------------------------- launch
extern "C" void kernel_launch(void* const* d_in, const int* in_sizes, int n_in,
                              void* d_out, int out_size, void* d_ws, size_t ws_size,
                              hipStream_t stream) {
  (void)in_sizes; (void)n_in; (void)out_size;
  const float* x      = (const float*)d_in[0];
  const float* w_qkv  = (const float*)d_in[1];
  const float* b_qkv  = (const float*)d_in[2];
  const float* w_out  = (const float*)d_in[3];
  const float* b_out  = (const float*)d_in[4];
  const float* w_ffn1 = (const float*)d_in[5];
  const float* b_ffn1 = (const float*)d_in[6];
  const float* w_ffn2 = (const float*)d_in[7];
  const float* b_ffn2 = (const float*)d_in[8];
  const float* g1     = (const float*)d_in[9];
  const float* be1    = (const float*)d_in[10];
  const float* g2     = (const float*)d_in[11];
  const float* be2    = (const float*)d_in[12];

  char* ws = (char*)d_ws;
  constexpr size_t WT_QKV_OFF  = 0;
  constexpr size_t WT_OUT_OFF  = WT_QKV_OFF  + 6291456;
  constexpr size_t WT_FFN1_OFF = WT_OUT_OFF  + 2097152;
  constexpr size_t WT_FFN2_OFF = WT_FFN1_OFF + 8388608;
  constexpr size_t KSTATP_OFF  = WT_FFN2_OFF + 8388608;
  constexpr size_t KSTAT_OFF   = KSTATP_OFF  + 262144;
  constexpr size_t KVP_OFF     = KSTAT_OFF   + 32768;
  constexpr size_t KVT_OFF     = KVP_OFF     + 8388608;
  constexpr size_t ACT1_OFF    = KVT_OFF     + 524288;
  constexpr size_t BIG_OFF     = ACT1_OFF    + 33554432;          // 67,928,064

  bf16_t* WT_QKV  = (bf16_t*)(ws + WT_QKV_OFF);
  bf16_t* WT_OUT  = (bf16_t*)(ws + WT_OUT_OFF);
  bf16_t* WT_FFN1 = (bf16_t*)(ws + WT_FFN1_OFF);
  bf16_t* WT_FFN2 = (bf16_t*)(ws + WT_FFN2_OFF);
  float2* KSTATP  = (float2*)(ws + KSTATP_OFF);
  float2* KSTAT   = (float2*)(ws + KSTAT_OFF);
  float*  KVP     = (float*) (ws + KVP_OFF);
  bf16_t* KVT     = (bf16_t*)(ws + KVT_OFF);
  bf16_t* ACT1    = (bf16_t*)(ws + ACT1_OFF);
  bf16_t* QKV     = (bf16_t*)(ws + BIG_OFF);   // 96 MB
  bf16_t* GACT    = (bf16_t*)(ws + BIG_OFF);   // up to 128 MB, after QKV dead
  float*  Y       = (float*)  d_out;           // residual mid-buffer lives in d_out

  const bool big_ws = ws_size >= (size_t)(BIG_OFF + 134217728ull);

  wtrans<<<dim3(3072 / 32, 1024 / 32), dim3(32, 8), 0, stream>>>(w_qkv,  WT_QKV,  1024, 3072);
  wtrans<<<dim3(1024 / 32, 1024 / 32), dim3(32, 8), 0, stream>>>(w_out,  WT_OUT,  1024, 1024);
  wtrans<<<dim3(4096 / 32, 1024 / 32), dim3(32, 8), 0, stream>>>(w_ffn1, WT_FFN1, 1024, 4096);
  wtrans<<<dim3(1024 / 32, 4096 / 32), dim3(32, 8), 0, stream>>>(w_ffn2, WT_FFN2, 4096, 1024);

  ln_kernel<<<NROWS, 256, 0, stream>>>(x, g1, be1, ACT1);

  // qkv = ln1 @ WqkvT + b
  gemm256<0><<<dim3(3072 / 256, NROWS / 256), 512, 0, stream>>>(ACT1, WT_QKV, b_qkv, nullptr, QKV, NROWS, 3072, 1024);

  qsoftmax<<<NROWS, 256, 0, stream>>>(QKV);
  kstats_partial<<<dim3(64, 8), 256, 0, stream>>>(QKV, KSTATP);
  kstats_merge<<<64, 64, 0, stream>>>(KSTATP, KSTAT);
  kv_partial<<<dim3(64, 8), 256, 0, stream>>>(QKV, KSTAT, KVP);
  kv_reduce<<<64, 256, 0, stream>>>(KVP, KVT);
  attn_apply<<<dim3(64, SS / 128), 256, 0, stream>>>(QKV, KVT, ACT1);

  // y = x + attn_cat @ WoutT + b  -> d_out  (QKV now dead)
  gemm256<1><<<dim3(1024 / 256, NROWS / 256), 512, 0, stream>>>(ACT1, WT_OUT, b_out, x, Y, NROWS, 1024, 1024);

  ln_kernel<<<NROWS, 256, 0, stream>>>(Y, g2, be2, ACT1);

  if (big_ws) {
    gemm256<2><<<dim3(4096 / 256, NROWS / 256), 512, 0, stream>>>(ACT1, WT_FFN1, b_ffn1, nullptr, GACT, NROWS, 4096, 1024);
    gemm256<1><<<dim3(1024 / 256, NROWS / 256), 512, 0, stream>>>(GACT, WT_FFN2, b_ffn2, x, (float*)d_out, NROWS, 1024, 4096);
  } else {
    for (int c = 0; c < 2; ++c) {
      const long r0 = (long)c * 8192;
      gemm256<2><<<dim3(4096 / 256, 8192 / 256), 512, 0, stream>>>(
          ACT1 + r0 * 1024, WT_FFN1, b_ffn1, nullptr, GACT, 8192, 4096, 1024);
      gemm256<1><<<dim3(1024 / 256, 8192 / 256), 512, 0, stream>>>(
          GACT, WT_FFN2, b_ffn2, x + r0 * 1024, (float*)d_out + r0 * 1024, 8192, 1024, 4096);
    }
  }
}

// Round 11
// 745.667 us; speedup vs baseline: 1.0688x; 1.0688x over previous
//
#include <hip/hip_runtime.h>
#include <hip/hip_bf16.h>
#include <cstdint>
#include <cstddef>

#define DIMC 1024
#define HEADS 16
#define HD 64
#define DFF 4096
#define BB 4
#define SS 4096
#define NROWS (BB*SS)   // 16384

typedef __bf16 bf16_t;
typedef __bf16 bf16x8 __attribute__((ext_vector_type(8)));
typedef __bf16 bf16x4 __attribute__((ext_vector_type(4)));
typedef float  f32x4  __attribute__((ext_vector_type(4)));

#define GLDS16(gp, lp) \
  __builtin_amdgcn_global_load_lds((const __attribute__((address_space(1))) void*)(gp), \
                                   (__attribute__((address_space(3))) void*)(lp), 16, 0, 0)

#define MFMA16(a, b, c) __builtin_amdgcn_mfma_f32_16x16x32_bf16((a), (b), (c), 0, 0, 0)

// ---------------------------------------------------------------- weight transpose f32[K][N] -> bf16[N][K]
__global__ __launch_bounds__(256) void wtrans(const float* __restrict__ W, bf16_t* __restrict__ Wt,
                                              int K, int N) {
  __shared__ float tile[32][33];
  int c0 = blockIdx.x * 32, r0 = blockIdx.y * 32;
  int tx = threadIdx.x, ty = threadIdx.y;
  #pragma unroll
  for (int i = 0; i < 32; i += 8)
    tile[ty + i][tx] = W[(long)(r0 + ty + i) * N + c0 + tx];
  __syncthreads();
  #pragma unroll
  for (int i = 0; i < 32; i += 8)
    Wt[(long)(c0 + ty + i) * K + r0 + tx] = (bf16_t)tile[tx][ty + i];
}

// ---------------------------------------------------------------- LayerNorm f32 row -> bf16 row
__global__ __launch_bounds__(256) void ln_kernel(const float* __restrict__ in,
                                                 const float* __restrict__ gamma,
                                                 const float* __restrict__ beta,
                                                 bf16_t* __restrict__ out) {
  long r = blockIdx.x;
  int t = threadIdx.x;
  float4 v = ((const float4*)(in + r * DIMC))[t];
  float s  = v.x + v.y + v.z + v.w;
  float sq = v.x * v.x + v.y * v.y + v.z * v.z + v.w * v.w;
  #pragma unroll
  for (int o = 32; o > 0; o >>= 1) { s += __shfl_xor(s, o); sq += __shfl_xor(sq, o); }
  __shared__ float red[8];
  if ((t & 63) == 0) { red[(t >> 6) * 2] = s; red[(t >> 6) * 2 + 1] = sq; }
  __syncthreads();
  s  = red[0] + red[2] + red[4] + red[6];
  sq = red[1] + red[3] + red[5] + red[7];
  float mu  = s * (1.0f / DIMC);
  float var = sq * (1.0f / DIMC) - mu * mu;
  float rs  = 1.0f / sqrtf(var + 1e-5f);
  float4 g  = ((const float4*)gamma)[t];
  float4 bb = ((const float4*)beta)[t];
  bf16x4 o;
  o[0] = (bf16_t)((v.x - mu) * rs * g.x + bb.x);
  o[1] = (bf16_t)((v.y - mu) * rs * g.y + bb.y);
  o[2] = (bf16_t)((v.z - mu) * rs * g.z + bb.z);
  o[3] = (bf16_t)((v.w - mu) * rs * g.w + bb.w);
  ((bf16x4*)(out + r * DIMC))[t] = o;
}

// ---------------------------------------------------------------- GEMM: A[M][K] bf16 @ Bt[N][K] bf16 -> epilogue
// r4-proven 128x128 structure (33.7% MfmaUtil, multi-block/CU overlap) + XCD swizzle +
// lane-constant XOR LDS swizzle (8-way -> 2-way bank conflicts, zero instruction cost).
// MODE 0: bf16 out = acc + bias   MODE 1: f32 out = acc + bias + resid   MODE 2: bf16 out = gelu(acc+bias)
template <int MODE>
__global__ __launch_bounds__(256, 2) void gemm_bt(const bf16_t* __restrict__ A,
                                                  const bf16_t* __restrict__ Bt,
                                                  const float* __restrict__ bias,
                                                  const float* __restrict__ resid,
                                                  void* __restrict__ outp,
                                                  int M, int N, int K) {
  __shared__ bf16_t As[128 * 32];
  __shared__ bf16_t Bs[128 * 32];
  const int t = threadIdx.x;
  const int lane = t & 63;
  const int wave = t >> 6;

  // T1: bijective XCD swizzle (all nwg here %8==0, gridDim.x %4==0) + 8-row x 4-col grouping
  const int nwg  = gridDim.x * gridDim.y;
  const int bid0 = blockIdx.y * gridDim.x + blockIdx.x;
  const int lg   = (bid0 & 7) * (nwg >> 3) + (bid0 >> 3);
  const int span = (int)gridDim.y << 2;
  const int gidx = lg / span;
  const int rem  = lg - gidx * span;
  const long arow0 = (long)(rem >> 2) * 128;
  const long brow0 = (long)((gidx << 2) + (rem & 3)) * 128;

  const int wm = (wave >> 1) * 64, wn = (wave & 1) * 64;

  f32x4 acc[4][4] = {};
  const int c0 = t, c1 = t + 256;           // 16B chunks: row=c>>2, chunk=(c&3)
  const int fr = lane & 15;
  const int q4 = lane >> 4;
  const int kq = (q4 ^ ((fr >> 1) & 3)) * 8;        // swizzled read chunk (elements)

  // staging source chunks XOR'd by row parity (dest linear; rule #21 pair with kq)
  const int r0s = c0 >> 2, ch0 = ((c0 & 3) ^ ((r0s >> 1) & 3)) * 8;
  const int r1s = c1 >> 2, ch1 = ((c1 & 3) ^ ((r1s >> 1) & 3)) * 8;

  for (int kt = 0; kt < K; kt += 32) {
    {
      GLDS16(A  + (arow0 + r0s) * K + kt + ch0, &As[c0 * 8]);
      GLDS16(A  + (arow0 + r1s) * K + kt + ch1, &As[c1 * 8]);
      GLDS16(Bt + (brow0 + r0s) * K + kt + ch0, &Bs[c0 * 8]);
      GLDS16(Bt + (brow0 + r1s) * K + kt + ch1, &Bs[c1 * 8]);
    }
    asm volatile("s_waitcnt vmcnt(0)" ::: "memory");
    __syncthreads();
    bf16x8 a[4], b[4];
    #pragma unroll
    for (int i = 0; i < 4; ++i) {
      a[i] = *(const bf16x8*)&As[(wm + i * 16 + fr) * 32 + kq];
      b[i] = *(const bf16x8*)&Bs[(wn + i * 16 + fr) * 32 + kq];
    }
    #pragma unroll
    for (int i = 0; i < 4; ++i)
      #pragma unroll
      for (int j = 0; j < 4; ++j)
        acc[i][j] = MFMA16(a[i], b[j], acc[i][j]);
    __syncthreads();
  }

  const int rq = q4 * 4;
  #pragma unroll
  for (int i = 0; i < 4; ++i) {
    #pragma unroll
    for (int j = 0; j < 4; ++j) {
      long col = brow0 + wn + j * 16 + fr;
      float bv = bias[col];
      #pragma unroll
      for (int r = 0; r < 4; ++r) {
        long row = arow0 + wm + i * 16 + rq + r;
        float v = acc[i][j][r] + bv;
        if (MODE == 0) {
          ((bf16_t*)outp)[row * N + col] = (bf16_t)v;
        } else if (MODE == 1) {
          ((float*)outp)[row * N + col] = v + resid[row * N + col];
        } else {
          float g = 0.5f * v * (1.0f + erff(v * 0.70710678118654752f));
          ((bf16_t*)outp)[row * N + col] = (bf16_t)g;
        }
      }
    }
  }
}

// ---------------------------------------------------------------- q softmax (in-place, per (row, head) over 64)
__global__ __launch_bounds__(256) void qsoftmax(bf16_t* __restrict__ qkv) {
  long r = blockIdx.x;
  int t = threadIdx.x, h = t >> 4, l = t & 15;
  bf16_t* p = qkv + r * 3072 + h * 64 + l * 4;
  bf16x4 v4 = *(const bf16x4*)p;
  float v0 = v4[0], v1 = v4[1], v2 = v4[2], v3 = v4[3];
  float m = fmaxf(fmaxf(v0, v1), fmaxf(v2, v3));
  #pragma unroll
  for (int o = 8; o >= 1; o >>= 1) m = fmaxf(m, __shfl_xor(m, o));
  float e0 = __expf(v0 - m), e1 = __expf(v1 - m), e2 = __expf(v2 - m), e3 = __expf(v3 - m);
  float s = e0 + e1 + e2 + e3;
  #pragma unroll
  for (int o = 8; o >= 1; o >>= 1) s += __shfl_xor(s, o);
  float inv = 1.0f / s;
  bf16x4 o4;
  o4[0] = (bf16_t)(e0 * inv); o4[1] = (bf16_t)(e1 * inv);
  o4[2] = (bf16_t)(e2 * inv); o4[3] = (bf16_t)(e3 * inv);
  *(bf16x4*)p = o4;
}

// ---------------------------------------------------------------- k column-softmax stats (online max/sum partials)
__global__ __launch_bounds__(256) void kstats_partial(const bf16_t* __restrict__ qkv,
                                                      float2* __restrict__ part) {
  int bh = blockIdx.x, ch = blockIdx.y;
  int b = bh >> 4, h = bh & 15;
  int t = threadIdx.x, d = t & 63, sr = t >> 6;
  const bf16_t* kp = qkv + (long)b * SS * 3072 + 1024 + h * 64 + d;
  float m = -INFINITY, sum = 0.f;
  for (int s = ch * 512 + sr; s < ch * 512 + 512; s += 4) {
    float v = (float)kp[(long)s * 3072];
    float nm = fmaxf(m, v);
    sum = sum * __expf(m - nm) + __expf(v - nm);
    m = nm;
  }
  __shared__ float2 red[4][64];
  red[sr][d] = make_float2(m, sum);
  __syncthreads();
  if (t < 64) {
    float2 a = red[0][t];
    #pragma unroll
    for (int i = 1; i < 4; ++i) {
      float2 p = red[i][t];
      float nm = fmaxf(a.x, p.x);
      a.y = a.y * __expf(a.x - nm) + p.y * __expf(p.x - nm);
      a.x = nm;
    }
    part[(long)(bh * 8 + ch) * 64 + t] = a;
  }
}

__global__ void kstats_merge(const float2* __restrict__ part, float2* __restrict__ stat) {
  int bh = blockIdx.x, d = threadIdx.x;  // 64 threads
  float m = -INFINITY, s = 0.f;
  #pragma unroll
  for (int c = 0; c < 8; ++c) {
    float2 p = part[(long)(bh * 8 + c) * 64 + d];
    float nm = fmaxf(m, p.x);
    s = s * __expf(m - nm) + p.y * __expf(p.x - nm);
    m = nm;
  }
  stat[bh * 64 + d] = make_float2(m, 1.0f / s);
}

// ---------------------------------------------------------------- kv = sum_s softmax_k[s,d] * v[s,e]  (partials over s-chunks)
__global__ __launch_bounds__(256) void kv_partial(const bf16_t* __restrict__ qkv,
                                                  const float2* __restrict__ stat,
                                                  float* __restrict__ kvp) {
  int bh = blockIdx.x, ch = blockIdx.y;
  int b = bh >> 4, h = bh & 15;
  int t = threadIdx.x;
  __shared__ float  Kexp[64][65];
  __shared__ bf16_t Vs[64][72];
  __shared__ float  kmaxs[64], kinvs[64];
  if (t < 64) { float2 p = stat[bh * 64 + t]; kmaxs[t] = p.x; kinvs[t] = p.y; }
  int rowl = t >> 2, c0 = (t & 3) * 16;
  int dd = t >> 2, e0 = (t & 3) * 16;
  float acc[16] = {};
  for (int sb = 0; sb < 8; ++sb) {
    long s = (long)ch * 512 + sb * 64 + rowl;
    const bf16_t* base = qkv + ((long)b * SS + s) * 3072 + h * 64;
    bf16x8 k0 = *(const bf16x8*)(base + 1024 + c0);
    bf16x8 k1 = *(const bf16x8*)(base + 1024 + c0 + 8);
    bf16x8 v0 = *(const bf16x8*)(base + 2048 + c0);
    bf16x8 v1 = *(const bf16x8*)(base + 2048 + c0 + 8);
    __syncthreads();
    #pragma unroll
    for (int j = 0; j < 8; ++j) {
      Kexp[rowl][c0 + j]     = __expf((float)k0[j] - kmaxs[c0 + j]) * kinvs[c0 + j];
      Kexp[rowl][c0 + 8 + j] = __expf((float)k1[j] - kmaxs[c0 + 8 + j]) * kinvs[c0 + 8 + j];
    }
    *(bf16x8*)&Vs[rowl][c0]     = v0;
    *(bf16x8*)&Vs[rowl][c0 + 8] = v1;
    __syncthreads();
    for (int ls = 0; ls < 64; ++ls) {
      float kd = Kexp[ls][dd];
      bf16x8 va = *(const bf16x8*)&Vs[ls][e0];
      bf16x8 vb = *(const bf16x8*)&Vs[ls][e0 + 8];
      #pragma unroll
      for (int j = 0; j < 8; ++j) {
        acc[j]     += kd * (float)va[j];
        acc[j + 8] += kd * (float)vb[j];
      }
    }
  }
  float* dst = kvp + (long)(bh * 8 + ch) * 4096 + dd * 64 + e0;
  #pragma unroll
  for (int j = 0; j < 16; ++j) dst[j] = acc[j];
}

// reduce partials, store TRANSPOSED bf16: kvT[bh][e][d]
__global__ void kv_reduce(const float* __restrict__ kvp, bf16_t* __restrict__ kvT) {
  int bh = blockIdx.x, t = threadIdx.x;
  for (int p = t; p < 4096; p += 256) {
    int d = p >> 6, e = p & 63;
    float s = 0.f;
    #pragma unroll
    for (int c = 0; c < 8; ++c) s += kvp[(long)(bh * 8 + c) * 4096 + p];
    kvT[(long)bh * 4096 + e * 64 + d] = (bf16_t)s;
  }
}

// ---------------------------------------------------------------- out[s,e] = q_sm[s,:] @ kv[:,e]  via MFMA, per (b,h)
__global__ __launch_bounds__(256) void attn_apply(const bf16_t* __restrict__ qkv,
                                                  const bf16_t* __restrict__ kvT,
                                                  bf16_t* __restrict__ attn) {
  int bh = blockIdx.x, sc = blockIdx.y;
  int b = bh >> 4, h = bh & 15;
  int t = threadIdx.x, lane = t & 63, w = t >> 6;
  __shared__ bf16_t kvs[64 * 64];
  for (int i = t * 8; i < 4096; i += 256 * 8)
    *(bf16x8*)&kvs[i] = *(const bf16x8*)(kvT + (long)bh * 4096 + i);
  __syncthreads();
  int fr = lane & 15, kq = (lane >> 4) * 8;
  long qrow = (long)b * SS + sc * 128 + w * 32;
  f32x4 acc[2][4] = {};
  #pragma unroll
  for (int kk = 0; kk < 2; ++kk) {
    bf16x8 a0 = *(const bf16x8*)(qkv + (qrow + fr) * 3072      + h * 64 + kk * 32 + kq);
    bf16x8 a1 = *(const bf16x8*)(qkv + (qrow + 16 + fr) * 3072 + h * 64 + kk * 32 + kq);
    #pragma unroll
    for (int j = 0; j < 4; ++j) {
      bf16x8 bfr = *(const bf16x8*)&kvs[(j * 16 + fr) * 64 + kk * 32 + kq];
      acc[0][j] = MFMA16(a0, bfr, acc[0][j]);
      acc[1][j] = MFMA16(a1, bfr, acc[1][j]);
    }
  }
  int rq = (lane >> 4) * 4;
  #pragma unroll
  for (int i = 0; i < 2; ++i)
    #pragma unroll
    for (int j = 0; j < 4; ++j)
      #pragma unroll
      for (int r = 0; r < 4; ++r)
        attn[(qrow + i * 16 + rq + r) * 1024 + h * 64 + j * 16 + fr] = (bf16_t)acc[i][j][r];
}

// ---------------------------------------------------------------- launch
extern "C" void kernel_launch(void* const* d_in, const int* in_sizes, int n_in,
                              void* d_out, int out_size, void* d_ws, size_t ws_size,
                              hipStream_t stream) {
  (void)in_sizes; (void)n_in; (void)out_size;
  const float* x      = (const float*)d_in[0];
  const float* w_qkv  = (const float*)d_in[1];
  const float* b_qkv  = (const float*)d_in[2];
  const float* w_out  = (const float*)d_in[3];
  const float* b_out  = (const float*)d_in[4];
  const float* w_ffn1 = (const float*)d_in[5];
  const float* b_ffn1 = (const float*)d_in[6];
  const float* w_ffn2 = (const float*)d_in[7];
  const float* b_ffn2 = (const float*)d_in[8];
  const float* g1     = (const float*)d_in[9];
  const float* be1    = (const float*)d_in[10];
  const float* g2     = (const float*)d_in[11];
  const float* be2    = (const float*)d_in[12];

  char* ws = (char*)d_ws;
  constexpr size_t WT_QKV_OFF  = 0;
  constexpr size_t WT_OUT_OFF  = WT_QKV_OFF  + 6291456;
  constexpr size_t WT_FFN1_OFF = WT_OUT_OFF  + 2097152;
  constexpr size_t WT_FFN2_OFF = WT_FFN1_OFF + 8388608;
  constexpr size_t KSTATP_OFF  = WT_FFN2_OFF + 8388608;
  constexpr size_t KSTAT_OFF   = KSTATP_OFF  + 262144;
  constexpr size_t KVP_OFF     = KSTAT_OFF   + 32768;
  constexpr size_t KVT_OFF     = KVP_OFF     + 8388608;
  constexpr size_t ACT1_OFF    = KVT_OFF     + 524288;
  constexpr size_t BIG_OFF     = ACT1_OFF    + 33554432;          // 67,928,064

  bf16_t* WT_QKV  = (bf16_t*)(ws + WT_QKV_OFF);
  bf16_t* WT_OUT  = (bf16_t*)(ws + WT_OUT_OFF);
  bf16_t* WT_FFN1 = (bf16_t*)(ws + WT_FFN1_OFF);
  bf16_t* WT_FFN2 = (bf16_t*)(ws + WT_FFN2_OFF);
  float2* KSTATP  = (float2*)(ws + KSTATP_OFF);
  float2* KSTAT   = (float2*)(ws + KSTAT_OFF);
  float*  KVP     = (float*) (ws + KVP_OFF);
  bf16_t* KVT     = (bf16_t*)(ws + KVT_OFF);
  bf16_t* ACT1    = (bf16_t*)(ws + ACT1_OFF);
  bf16_t* QKV     = (bf16_t*)(ws + BIG_OFF);   // 96 MB
  bf16_t* GACT    = (bf16_t*)(ws + BIG_OFF);   // up to 128 MB, after QKV dead
  float*  Y       = (float*)  d_out;           // residual mid-buffer lives in d_out

  const bool big_ws = ws_size >= (size_t)(BIG_OFF + 134217728ull);

  wtrans<<<dim3(3072 / 32, 1024 / 32), dim3(32, 8), 0, stream>>>(w_qkv,  WT_QKV,  1024, 3072);
  wtrans<<<dim3(1024 / 32, 1024 / 32), dim3(32, 8), 0, stream>>>(w_out,  WT_OUT,  1024, 1024);
  wtrans<<<dim3(4096 / 32, 1024 / 32), dim3(32, 8), 0, stream>>>(w_ffn1, WT_FFN1, 1024, 4096);
  wtrans<<<dim3(1024 / 32, 4096 / 32), dim3(32, 8), 0, stream>>>(w_ffn2, WT_FFN2, 4096, 1024);

  ln_kernel<<<NROWS, 256, 0, stream>>>(x, g1, be1, ACT1);

  // qkv = ln1 @ WqkvT + b   (grid 24 x 128, nwg=3072 %8==0, Gx%4==0)
  gemm_bt<0><<<dim3(3072 / 128, NROWS / 128), 256, 0, stream>>>(ACT1, WT_QKV, b_qkv, nullptr, QKV, NROWS, 3072, 1024);

  qsoftmax<<<NROWS, 256, 0, stream>>>(QKV);
  kstats_partial<<<dim3(64, 8), 256, 0, stream>>>(QKV, KSTATP);
  kstats_merge<<<64, 64, 0, stream>>>(KSTATP, KSTAT);
  kv_partial<<<dim3(64, 8), 256, 0, stream>>>(QKV, KSTAT, KVP);
  kv_reduce<<<64, 256, 0, stream>>>(KVP, KVT);
  attn_apply<<<dim3(64, SS / 128), 256, 0, stream>>>(QKV, KVT, ACT1);

  // y = x + attn_cat @ WoutT + b  -> d_out  (grid 8 x 128)
  gemm_bt<1><<<dim3(1024 / 128, NROWS / 128), 256, 0, stream>>>(ACT1, WT_OUT, b_out, x, Y, NROWS, 1024, 1024);

  ln_kernel<<<NROWS, 256, 0, stream>>>(Y, g2, be2, ACT1);

  if (big_ws) {
    // full-width FFN: ffn1 grid 32 x 128 (4096 blocks), ffn2 grid 8 x 128 (1024 blocks)
    gemm_bt<2><<<dim3(4096 / 128, NROWS / 128), 256, 0, stream>>>(ACT1, WT_FFN1, b_ffn1, nullptr, GACT, NROWS, 4096, 1024);
    gemm_bt<1><<<dim3(1024 / 128, NROWS / 128), 256, 0, stream>>>(GACT, WT_FFN2, b_ffn2, x, (float*)d_out, NROWS, 1024, 4096);
  } else {
    // fallback: two 8192-row chunks (GACT 64 MB); grids 32x64 and 8x64 (nwg %8==0, Gx%4==0)
    for (int c = 0; c < 2; ++c) {
      const long r0 = (long)c * 8192;
      gemm_bt<2><<<dim3(4096 / 128, 8192 / 128), 256, 0, stream>>>(
          ACT1 + r0 * 1024, WT_FFN1, b_ffn1, nullptr, GACT, 8192, 4096, 1024);
      gemm_bt<1><<<dim3(1024 / 128, 8192 / 128), 256, 0, stream>>>(
          GACT, WT_FFN2, b_ffn2, x + r0 * 1024, (float*)d_out + r0 * 1024, 8192, 1024, 4096);
    }
  }
}

// Round 12
// 719.067 us; speedup vs baseline: 1.1084x; 1.0370x over previous
//
#include <hip/hip_runtime.h>
#include <hip/hip_bf16.h>
#include <cstdint>
#include <cstddef>

#define DIMC 1024
#define HEADS 16
#define HD 64
#define DFF 4096
#define BB 4
#define SS 4096
#define NROWS (BB*SS)   // 16384

typedef __bf16 bf16_t;
typedef __bf16 bf16x8 __attribute__((ext_vector_type(8)));
typedef __bf16 bf16x4 __attribute__((ext_vector_type(4)));
typedef float  f32x4  __attribute__((ext_vector_type(4)));

#define GLDS16(gp, lp) \
  __builtin_amdgcn_global_load_lds((const __attribute__((address_space(1))) void*)(gp), \
                                   (__attribute__((address_space(3))) void*)(lp), 16, 0, 0)

#define MFMA16(a, b, c) __builtin_amdgcn_mfma_f32_16x16x32_bf16((a), (b), (c), 0, 0, 0)

// fast erf, Abramowitz-Stegun 7.1.26, |abs err| <= 1.5e-7
__device__ __forceinline__ float fast_erf(float x) {
  float ax = fabsf(x);
  float t  = __builtin_amdgcn_rcpf(fmaf(0.3275911f, ax, 1.0f));
  float p  = t * fmaf(t, fmaf(t, fmaf(t, fmaf(t, 1.061405429f, -1.453152027f),
                                      1.421413741f), -0.284496736f), 0.254829592f);
  float er = 1.0f - p * __expf(-ax * ax);
  return copysignf(er, x);
}

// ---------------------------------------------------------------- weight transpose f32[K][N] -> bf16[N][K]
__global__ __launch_bounds__(256) void wtrans(const float* __restrict__ W, bf16_t* __restrict__ Wt,
                                              int K, int N) {
  __shared__ float tile[32][33];
  int c0 = blockIdx.x * 32, r0 = blockIdx.y * 32;
  int tx = threadIdx.x, ty = threadIdx.y;
  #pragma unroll
  for (int i = 0; i < 32; i += 8)
    tile[ty + i][tx] = W[(long)(r0 + ty + i) * N + c0 + tx];
  __syncthreads();
  #pragma unroll
  for (int i = 0; i < 32; i += 8)
    Wt[(long)(c0 + ty + i) * K + r0 + tx] = (bf16_t)tile[tx][ty + i];
}

// ---------------------------------------------------------------- LayerNorm f32 row -> bf16 row
__global__ __launch_bounds__(256) void ln_kernel(const float* __restrict__ in,
                                                 const float* __restrict__ gamma,
                                                 const float* __restrict__ beta,
                                                 bf16_t* __restrict__ out) {
  long r = blockIdx.x;
  int t = threadIdx.x;
  float4 v = ((const float4*)(in + r * DIMC))[t];
  float s  = v.x + v.y + v.z + v.w;
  float sq = v.x * v.x + v.y * v.y + v.z * v.z + v.w * v.w;
  #pragma unroll
  for (int o = 32; o > 0; o >>= 1) { s += __shfl_xor(s, o); sq += __shfl_xor(sq, o); }
  __shared__ float red[8];
  if ((t & 63) == 0) { red[(t >> 6) * 2] = s; red[(t >> 6) * 2 + 1] = sq; }
  __syncthreads();
  s  = red[0] + red[2] + red[4] + red[6];
  sq = red[1] + red[3] + red[5] + red[7];
  float mu  = s * (1.0f / DIMC);
  float var = sq * (1.0f / DIMC) - mu * mu;
  float rs  = 1.0f / sqrtf(var + 1e-5f);
  float4 g  = ((const float4*)gamma)[t];
  float4 bb = ((const float4*)beta)[t];
  bf16x4 o;
  o[0] = (bf16_t)((v.x - mu) * rs * g.x + bb.x);
  o[1] = (bf16_t)((v.y - mu) * rs * g.y + bb.y);
  o[2] = (bf16_t)((v.z - mu) * rs * g.z + bb.z);
  o[3] = (bf16_t)((v.w - mu) * rs * g.w + bb.w);
  ((bf16x4*)(out + r * DIMC))[t] = o;
}

// ---------------------------------------------------------------- GEMM: A[M][K] bf16 @ Bt[N][K] bf16 -> epilogue
// r4-proven 128x128 structure + XCD swizzle + lane-constant XOR LDS swizzle (conflicts=0).
// MODE 0: bf16 = acc+bias     MODE 1: f32 = acc+bias+resid
// MODE 2: bf16 = gelu(acc+bias) (fast erf)
// MODE 3: bf16 = acc+bias, with per-(row,head) softmax fused for cols < 1024 (Q region)
template <int MODE>
__global__ __launch_bounds__(256, 2) void gemm_bt(const bf16_t* __restrict__ A,
                                                  const bf16_t* __restrict__ Bt,
                                                  const float* __restrict__ bias,
                                                  const float* __restrict__ resid,
                                                  void* __restrict__ outp,
                                                  int M, int N, int K) {
  __shared__ bf16_t As[128 * 32];
  __shared__ bf16_t Bs[128 * 32];
  const int t = threadIdx.x;
  const int lane = t & 63;
  const int wave = t >> 6;

  // T1: bijective XCD swizzle (all nwg here %8==0, gridDim.x %4==0) + 8-row x 4-col grouping
  const int nwg  = gridDim.x * gridDim.y;
  const int bid0 = blockIdx.y * gridDim.x + blockIdx.x;
  const int lg   = (bid0 & 7) * (nwg >> 3) + (bid0 >> 3);
  const int span = (int)gridDim.y << 2;
  const int gidx = lg / span;
  const int rem  = lg - gidx * span;
  const long arow0 = (long)(rem >> 2) * 128;
  const long brow0 = (long)((gidx << 2) + (rem & 3)) * 128;

  const int wm = (wave >> 1) * 64, wn = (wave & 1) * 64;

  f32x4 acc[4][4] = {};
  const int c0 = t, c1 = t + 256;           // 16B chunks: row=c>>2, chunk=(c&3)
  const int fr = lane & 15;
  const int q4 = lane >> 4;
  const int kq = (q4 ^ ((fr >> 1) & 3)) * 8;        // swizzled read chunk (elements)

  // staging source chunks XOR'd by row parity (dest linear; rule #21 pair with kq)
  const int r0s = c0 >> 2, ch0 = ((c0 & 3) ^ ((r0s >> 1) & 3)) * 8;
  const int r1s = c1 >> 2, ch1 = ((c1 & 3) ^ ((r1s >> 1) & 3)) * 8;

  for (int kt = 0; kt < K; kt += 32) {
    {
      GLDS16(A  + (arow0 + r0s) * K + kt + ch0, &As[c0 * 8]);
      GLDS16(A  + (arow0 + r1s) * K + kt + ch1, &As[c1 * 8]);
      GLDS16(Bt + (brow0 + r0s) * K + kt + ch0, &Bs[c0 * 8]);
      GLDS16(Bt + (brow0 + r1s) * K + kt + ch1, &Bs[c1 * 8]);
    }
    asm volatile("s_waitcnt vmcnt(0)" ::: "memory");
    __syncthreads();
    bf16x8 a[4], b[4];
    #pragma unroll
    for (int i = 0; i < 4; ++i) {
      a[i] = *(const bf16x8*)&As[(wm + i * 16 + fr) * 32 + kq];
      b[i] = *(const bf16x8*)&Bs[(wn + i * 16 + fr) * 32 + kq];
    }
    #pragma unroll
    for (int i = 0; i < 4; ++i)
      #pragma unroll
      for (int j = 0; j < 4; ++j)
        acc[i][j] = MFMA16(a[i], b[j], acc[i][j]);
    __syncthreads();
  }

  const int rq = q4 * 4;

  if (MODE == 3 && brow0 < 1024) {
    // fused q-softmax: each row's 64 head-cols live in lanes fr=0..15 (q4 fixed) x 4 j-regs
    float bv[4];
    #pragma unroll
    for (int j = 0; j < 4; ++j) bv[j] = bias[brow0 + wn + j * 16 + fr];
    #pragma unroll
    for (int i = 0; i < 4; ++i) {
      #pragma unroll
      for (int r = 0; r < 4; ++r) {
        float v[4];
        #pragma unroll
        for (int j = 0; j < 4; ++j) v[j] = acc[i][j][r] + bv[j];
        float m = fmaxf(fmaxf(v[0], v[1]), fmaxf(v[2], v[3]));
        #pragma unroll
        for (int o = 1; o <= 8; o <<= 1) m = fmaxf(m, __shfl_xor(m, o));
        float e[4], s = 0.f;
        #pragma unroll
        for (int j = 0; j < 4; ++j) { e[j] = __expf(v[j] - m); s += e[j]; }
        #pragma unroll
        for (int o = 1; o <= 8; o <<= 1) s += __shfl_xor(s, o);
        float inv = 1.0f / s;
        long row = arow0 + wm + i * 16 + rq + r;
        #pragma unroll
        for (int j = 0; j < 4; ++j)
          ((bf16_t*)outp)[row * N + brow0 + wn + j * 16 + fr] = (bf16_t)(e[j] * inv);
      }
    }
  } else {
    #pragma unroll
    for (int i = 0; i < 4; ++i) {
      #pragma unroll
      for (int j = 0; j < 4; ++j) {
        long col = brow0 + wn + j * 16 + fr;
        float bv = bias[col];
        #pragma unroll
        for (int r = 0; r < 4; ++r) {
          long row = arow0 + wm + i * 16 + rq + r;
          float v = acc[i][j][r] + bv;
          if (MODE == 0 || MODE == 3) {
            ((bf16_t*)outp)[row * N + col] = (bf16_t)v;
          } else if (MODE == 1) {
            ((float*)outp)[row * N + col] = v + resid[row * N + col];
          } else {
            float g = 0.5f * v * (1.0f + fast_erf(v * 0.70710678118654752f));
            ((bf16_t*)outp)[row * N + col] = (bf16_t)g;
          }
        }
      }
    }
  }
}

// ---------------------------------------------------------------- k column-softmax stats (online max/sum partials)
__global__ __launch_bounds__(256) void kstats_partial(const bf16_t* __restrict__ qkv,
                                                      float2* __restrict__ part) {
  int bh = blockIdx.x, ch = blockIdx.y;
  int b = bh >> 4, h = bh & 15;
  int t = threadIdx.x, d = t & 63, sr = t >> 6;
  const bf16_t* kp = qkv + (long)b * SS * 3072 + 1024 + h * 64 + d;
  float m = -INFINITY, sum = 0.f;
  for (int s = ch * 512 + sr; s < ch * 512 + 512; s += 4) {
    float v = (float)kp[(long)s * 3072];
    float nm = fmaxf(m, v);
    sum = sum * __expf(m - nm) + __expf(v - nm);
    m = nm;
  }
  __shared__ float2 red[4][64];
  red[sr][d] = make_float2(m, sum);
  __syncthreads();
  if (t < 64) {
    float2 a = red[0][t];
    #pragma unroll
    for (int i = 1; i < 4; ++i) {
      float2 p = red[i][t];
      float nm = fmaxf(a.x, p.x);
      a.y = a.y * __expf(a.x - nm) + p.y * __expf(p.x - nm);
      a.x = nm;
    }
    part[(long)(bh * 8 + ch) * 64 + t] = a;
  }
}

__global__ void kstats_merge(const float2* __restrict__ part, float2* __restrict__ stat) {
  int bh = blockIdx.x, d = threadIdx.x;  // 64 threads
  float m = -INFINITY, s = 0.f;
  #pragma unroll
  for (int c = 0; c < 8; ++c) {
    float2 p = part[(long)(bh * 8 + c) * 64 + d];
    float nm = fmaxf(m, p.x);
    s = s * __expf(m - nm) + p.y * __expf(p.x - nm);
    m = nm;
  }
  stat[bh * 64 + d] = make_float2(m, 1.0f / s);
}

// ---------------------------------------------------------------- kv = sum_s softmax_k[s,d] * v[s,e]  (partials over s-chunks)
__global__ __launch_bounds__(256) void kv_partial(const bf16_t* __restrict__ qkv,
                                                  const float2* __restrict__ stat,
                                                  float* __restrict__ kvp) {
  int bh = blockIdx.x, ch = blockIdx.y;
  int b = bh >> 4, h = bh & 15;
  int t = threadIdx.x;
  __shared__ float  Kexp[64][65];
  __shared__ bf16_t Vs[64][72];
  __shared__ float  kmaxs[64], kinvs[64];
  if (t < 64) { float2 p = stat[bh * 64 + t]; kmaxs[t] = p.x; kinvs[t] = p.y; }
  int rowl = t >> 2, c0 = (t & 3) * 16;
  int dd = t >> 2, e0 = (t & 3) * 16;
  float acc[16] = {};
  for (int sb = 0; sb < 8; ++sb) {
    long s = (long)ch * 512 + sb * 64 + rowl;
    const bf16_t* base = qkv + ((long)b * SS + s) * 3072 + h * 64;
    bf16x8 k0 = *(const bf16x8*)(base + 1024 + c0);
    bf16x8 k1 = *(const bf16x8*)(base + 1024 + c0 + 8);
    bf16x8 v0 = *(const bf16x8*)(base + 2048 + c0);
    bf16x8 v1 = *(const bf16x8*)(base + 2048 + c0 + 8);
    __syncthreads();
    #pragma unroll
    for (int j = 0; j < 8; ++j) {
      Kexp[rowl][c0 + j]     = __expf((float)k0[j] - kmaxs[c0 + j]) * kinvs[c0 + j];
      Kexp[rowl][c0 + 8 + j] = __expf((float)k1[j] - kmaxs[c0 + 8 + j]) * kinvs[c0 + 8 + j];
    }
    *(bf16x8*)&Vs[rowl][c0]     = v0;
    *(bf16x8*)&Vs[rowl][c0 + 8] = v1;
    __syncthreads();
    for (int ls = 0; ls < 64; ++ls) {
      float kd = Kexp[ls][dd];
      bf16x8 va = *(const bf16x8*)&Vs[ls][e0];
      bf16x8 vb = *(const bf16x8*)&Vs[ls][e0 + 8];
      #pragma unroll
      for (int j = 0; j < 8; ++j) {
        acc[j]     += kd * (float)va[j];
        acc[j + 8] += kd * (float)vb[j];
      }
    }
  }
  float* dst = kvp + (long)(bh * 8 + ch) * 4096 + dd * 64 + e0;
  #pragma unroll
  for (int j = 0; j < 16; ++j) dst[j] = acc[j];
}

// reduce partials, store TRANSPOSED bf16: kvT[bh][e][d]
__global__ void kv_reduce(const float* __restrict__ kvp, bf16_t* __restrict__ kvT) {
  int bh = blockIdx.x, t = threadIdx.x;
  for (int p = t; p < 4096; p += 256) {
    int d = p >> 6, e = p & 63;
    float s = 0.f;
    #pragma unroll
    for (int c = 0; c < 8; ++c) s += kvp[(long)(bh * 8 + c) * 4096 + p];
    kvT[(long)bh * 4096 + e * 64 + d] = (bf16_t)s;
  }
}

// ---------------------------------------------------------------- out[s,e] = q_sm[s,:] @ kv[:,e]  via MFMA, per (b,h)
__global__ __launch_bounds__(256) void attn_apply(const bf16_t* __restrict__ qkv,
                                                  const bf16_t* __restrict__ kvT,
                                                  bf16_t* __restrict__ attn) {
  int bh = blockIdx.x, sc = blockIdx.y;
  int b = bh >> 4, h = bh & 15;
  int t = threadIdx.x, lane = t & 63, w = t >> 6;
  __shared__ bf16_t kvs[64 * 64];
  for (int i = t * 8; i < 4096; i += 256 * 8)
    *(bf16x8*)&kvs[i] = *(const bf16x8*)(kvT + (long)bh * 4096 + i);
  __syncthreads();
  int fr = lane & 15, kq = (lane >> 4) * 8;
  long qrow = (long)b * SS + sc * 128 + w * 32;
  f32x4 acc[2][4] = {};
  #pragma unroll
  for (int kk = 0; kk < 2; ++kk) {
    bf16x8 a0 = *(const bf16x8*)(qkv + (qrow + fr) * 3072      + h * 64 + kk * 32 + kq);
    bf16x8 a1 = *(const bf16x8*)(qkv + (qrow + 16 + fr) * 3072 + h * 64 + kk * 32 + kq);
    #pragma unroll
    for (int j = 0; j < 4; ++j) {
      bf16x8 bfr = *(const bf16x8*)&kvs[(j * 16 + fr) * 64 + kk * 32 + kq];
      acc[0][j] = MFMA16(a0, bfr, acc[0][j]);
      acc[1][j] = MFMA16(a1, bfr, acc[1][j]);
    }
  }
  int rq = (lane >> 4) * 4;
  #pragma unroll
  for (int i = 0; i < 2; ++i)
    #pragma unroll
    for (int j = 0; j < 4; ++j)
      #pragma unroll
      for (int r = 0; r < 4; ++r)
        attn[(qrow + i * 16 + rq + r) * 1024 + h * 64 + j * 16 + fr] = (bf16_t)acc[i][j][r];
}

// ---------------------------------------------------------------- launch
extern "C" void kernel_launch(void* const* d_in, const int* in_sizes, int n_in,
                              void* d_out, int out_size, void* d_ws, size_t ws_size,
                              hipStream_t stream) {
  (void)in_sizes; (void)n_in; (void)out_size;
  const float* x      = (const float*)d_in[0];
  const float* w_qkv  = (const float*)d_in[1];
  const float* b_qkv  = (const float*)d_in[2];
  const float* w_out  = (const float*)d_in[3];
  const float* b_out  = (const float*)d_in[4];
  const float* w_ffn1 = (const float*)d_in[5];
  const float* b_ffn1 = (const float*)d_in[6];
  const float* w_ffn2 = (const float*)d_in[7];
  const float* b_ffn2 = (const float*)d_in[8];
  const float* g1     = (const float*)d_in[9];
  const float* be1    = (const float*)d_in[10];
  const float* g2     = (const float*)d_in[11];
  const float* be2    = (const float*)d_in[12];

  char* ws = (char*)d_ws;
  constexpr size_t WT_QKV_OFF  = 0;
  constexpr size_t WT_OUT_OFF  = WT_QKV_OFF  + 6291456;
  constexpr size_t WT_FFN1_OFF = WT_OUT_OFF  + 2097152;
  constexpr size_t WT_FFN2_OFF = WT_FFN1_OFF + 8388608;
  constexpr size_t KSTATP_OFF  = WT_FFN2_OFF + 8388608;
  constexpr size_t KSTAT_OFF   = KSTATP_OFF  + 262144;
  constexpr size_t KVP_OFF     = KSTAT_OFF   + 32768;
  constexpr size_t KVT_OFF     = KVP_OFF     + 8388608;
  constexpr size_t ACT1_OFF    = KVT_OFF     + 524288;
  constexpr size_t BIG_OFF     = ACT1_OFF    + 33554432;          // 67,928,064

  bf16_t* WT_QKV  = (bf16_t*)(ws + WT_QKV_OFF);
  bf16_t* WT_OUT  = (bf16_t*)(ws + WT_OUT_OFF);
  bf16_t* WT_FFN1 = (bf16_t*)(ws + WT_FFN1_OFF);
  bf16_t* WT_FFN2 = (bf16_t*)(ws + WT_FFN2_OFF);
  float2* KSTATP  = (float2*)(ws + KSTATP_OFF);
  float2* KSTAT   = (float2*)(ws + KSTAT_OFF);
  float*  KVP     = (float*) (ws + KVP_OFF);
  bf16_t* KVT     = (bf16_t*)(ws + KVT_OFF);
  bf16_t* ACT1    = (bf16_t*)(ws + ACT1_OFF);
  bf16_t* QKV     = (bf16_t*)(ws + BIG_OFF);   // 96 MB
  bf16_t* GACT    = (bf16_t*)(ws + BIG_OFF);   // up to 128 MB, after QKV dead
  float*  Y       = (float*)  d_out;           // residual mid-buffer lives in d_out

  const bool big_ws = ws_size >= (size_t)(BIG_OFF + 134217728ull);

  wtrans<<<dim3(3072 / 32, 1024 / 32), dim3(32, 8), 0, stream>>>(w_qkv,  WT_QKV,  1024, 3072);
  wtrans<<<dim3(1024 / 32, 1024 / 32), dim3(32, 8), 0, stream>>>(w_out,  WT_OUT,  1024, 1024);
  wtrans<<<dim3(4096 / 32, 1024 / 32), dim3(32, 8), 0, stream>>>(w_ffn1, WT_FFN1, 1024, 4096);
  wtrans<<<dim3(1024 / 32, 4096 / 32), dim3(32, 8), 0, stream>>>(w_ffn2, WT_FFN2, 4096, 1024);

  ln_kernel<<<NROWS, 256, 0, stream>>>(x, g1, be1, ACT1);

  // qkv = ln1 @ WqkvT + b, q-softmax fused in epilogue (grid 24 x 128)
  gemm_bt<3><<<dim3(3072 / 128, NROWS / 128), 256, 0, stream>>>(ACT1, WT_QKV, b_qkv, nullptr, QKV, NROWS, 3072, 1024);

  kstats_partial<<<dim3(64, 8), 256, 0, stream>>>(QKV, KSTATP);
  kstats_merge<<<64, 64, 0, stream>>>(KSTATP, KSTAT);
  kv_partial<<<dim3(64, 8), 256, 0, stream>>>(QKV, KSTAT, KVP);
  kv_reduce<<<64, 256, 0, stream>>>(KVP, KVT);
  attn_apply<<<dim3(64, SS / 128), 256, 0, stream>>>(QKV, KVT, ACT1);

  // y = x + attn_cat @ WoutT + b  -> d_out  (grid 8 x 128)
  gemm_bt<1><<<dim3(1024 / 128, NROWS / 128), 256, 0, stream>>>(ACT1, WT_OUT, b_out, x, Y, NROWS, 1024, 1024);

  ln_kernel<<<NROWS, 256, 0, stream>>>(Y, g2, be2, ACT1);

  if (big_ws) {
    // full-width FFN: ffn1 grid 32 x 128, ffn2 grid 8 x 128
    gemm_bt<2><<<dim3(4096 / 128, NROWS / 128), 256, 0, stream>>>(ACT1, WT_FFN1, b_ffn1, nullptr, GACT, NROWS, 4096, 1024);
    gemm_bt<1><<<dim3(1024 / 128, NROWS / 128), 256, 0, stream>>>(GACT, WT_FFN2, b_ffn2, x, (float*)d_out, NROWS, 1024, 4096);
  } else {
    for (int c = 0; c < 2; ++c) {
      const long r0 = (long)c * 8192;
      gemm_bt<2><<<dim3(4096 / 128, 8192 / 128), 256, 0, stream>>>(
          ACT1 + r0 * 1024, WT_FFN1, b_ffn1, nullptr, GACT, 8192, 4096, 1024);
      gemm_bt<1><<<dim3(1024 / 128, 8192 / 128), 256, 0, stream>>>(
          GACT, WT_FFN2, b_ffn2, x + r0 * 1024, (float*)d_out + r0 * 1024, 8192, 1024, 4096);
    }
  }
}

// Round 14
// 630.681 us; speedup vs baseline: 1.2637x; 1.1401x over previous
//
#include <hip/hip_runtime.h>
#include <hip/hip_bf16.h>
#include <cstdint>
#include <cstddef>

#define DIMC 1024
#define HEADS 16
#define HD 64
#define DFF 4096
#define BB 4
#define SS 4096
#define NROWS (BB*SS)   // 16384

typedef __bf16 bf16_t;
typedef __bf16 bf16x8 __attribute__((ext_vector_type(8)));
typedef __bf16 bf16x4 __attribute__((ext_vector_type(4)));
typedef float  f32x4  __attribute__((ext_vector_type(4)));

#define GLDS16(gp, lp) \
  __builtin_amdgcn_global_load_lds((const __attribute__((address_space(1))) void*)(gp), \
                                   (__attribute__((address_space(3))) void*)(lp), 16, 0, 0)

#define MFMA16(a, b, c) __builtin_amdgcn_mfma_f32_16x16x32_bf16((a), (b), (c), 0, 0, 0)

// fast erf, Abramowitz-Stegun 7.1.26, |abs err| <= 1.5e-7
__device__ __forceinline__ float fast_erf(float x) {
  float ax = fabsf(x);
  float t  = __builtin_amdgcn_rcpf(fmaf(0.3275911f, ax, 1.0f));
  float p  = t * fmaf(t, fmaf(t, fmaf(t, fmaf(t, 1.061405429f, -1.453152027f),
                                      1.421413741f), -0.284496736f), 0.254829592f);
  float er = 1.0f - p * __expf(-ax * ax);
  return copysignf(er, x);
}

// ---------------------------------------------------------------- weight transpose f32[K][N] -> bf16[N][K]
__global__ __launch_bounds__(256) void wtrans(const float* __restrict__ W, bf16_t* __restrict__ Wt,
                                              int K, int N) {
  __shared__ float tile[32][33];
  int c0 = blockIdx.x * 32, r0 = blockIdx.y * 32;
  int tx = threadIdx.x, ty = threadIdx.y;
  #pragma unroll
  for (int i = 0; i < 32; i += 8)
    tile[ty + i][tx] = W[(long)(r0 + ty + i) * N + c0 + tx];
  __syncthreads();
  #pragma unroll
  for (int i = 0; i < 32; i += 8)
    Wt[(long)(c0 + ty + i) * K + r0 + tx] = (bf16_t)tile[tx][ty + i];
}

// ---------------------------------------------------------------- LayerNorm f32 row -> bf16 row
__global__ __launch_bounds__(256) void ln_kernel(const float* __restrict__ in,
                                                 const float* __restrict__ gamma,
                                                 const float* __restrict__ beta,
                                                 bf16_t* __restrict__ out) {
  long r = blockIdx.x;
  int t = threadIdx.x;
  float4 v = ((const float4*)(in + r * DIMC))[t];
  float s  = v.x + v.y + v.z + v.w;
  float sq = v.x * v.x + v.y * v.y + v.z * v.z + v.w * v.w;
  #pragma unroll
  for (int o = 32; o > 0; o >>= 1) { s += __shfl_xor(s, o); sq += __shfl_xor(sq, o); }
  __shared__ float red[8];
  if ((t & 63) == 0) { red[(t >> 6) * 2] = s; red[(t >> 6) * 2 + 1] = sq; }
  __syncthreads();
  s  = red[0] + red[2] + red[4] + red[6];
  sq = red[1] + red[3] + red[5] + red[7];
  float mu  = s * (1.0f / DIMC);
  float var = sq * (1.0f / DIMC) - mu * mu;
  float rs  = 1.0f / sqrtf(var + 1e-5f);
  float4 g  = ((const float4*)gamma)[t];
  float4 bb = ((const float4*)beta)[t];
  bf16x4 o;
  o[0] = (bf16_t)((v.x - mu) * rs * g.x + bb.x);
  o[1] = (bf16_t)((v.y - mu) * rs * g.y + bb.y);
  o[2] = (bf16_t)((v.z - mu) * rs * g.z + bb.z);
  o[3] = (bf16_t)((v.w - mu) * rs * g.w + bb.w);
  ((bf16x4*)(out + r * DIMC))[t] = o;
}

// ---------------------------------------------------------------- GEMM: A[M][K] bf16 @ Bt[N][K] bf16 -> epilogue
// 128x128 tile, BK=64 (half the barrier/drain count of BK=32), XCD swizzle,
// XOR LDS swizzle on 8 chunks/row (conflict-free), multi-block/CU.
// MODE 0: bf16 = acc+bias     MODE 1: f32 = acc+bias+resid
// MODE 2: bf16 = gelu(acc+bias) (fast erf)
// MODE 3: bf16 = acc+bias, with per-(row,head) softmax fused for cols < 1024 (Q region)
template <int MODE>
__global__ __launch_bounds__(256, 2) void gemm_bt(const bf16_t* __restrict__ A,
                                                  const bf16_t* __restrict__ Bt,
                                                  const float* __restrict__ bias,
                                                  const float* __restrict__ resid,
                                                  void* __restrict__ outp,
                                                  int M, int N, int K) {
  __shared__ bf16_t As[128 * 64];
  __shared__ bf16_t Bs[128 * 64];
  const int t = threadIdx.x;
  const int lane = t & 63;
  const int wave = t >> 6;

  // T1: bijective XCD swizzle (all nwg here %8==0, gridDim.x %4==0) + 8-row x 4-col grouping
  const int nwg  = gridDim.x * gridDim.y;
  const int bid0 = blockIdx.y * gridDim.x + blockIdx.x;
  const int lg   = (bid0 & 7) * (nwg >> 3) + (bid0 >> 3);
  const int span = (int)gridDim.y << 2;
  const int gidx = lg / span;
  const int rem  = lg - gidx * span;
  const long arow0 = (long)(rem >> 2) * 128;
  const long brow0 = (long)((gidx << 2) + (rem & 3)) * 128;

  const int wm = (wave >> 1) * 64, wn = (wave & 1) * 64;

  f32x4 acc[4][4] = {};
  const int fr  = lane & 15;
  const int q4  = lane >> 4;
  const int frl = fr & 7;
  const int cr0 = ((q4    ) ^ frl) * 8;   // element offset of k-half-0 chunk
  const int cr1 = ((q4 + 4) ^ frl) * 8;   // element offset of k-half-1 chunk

  for (int kt = 0; kt < K; kt += 64) {
    #pragma unroll
    for (int p = 0; p < 4; ++p) {
      const int c = t + 256 * p;
      const int row = c >> 3;
      const int gch = ((c & 7) ^ (row & 7)) * 8;   // source chunk XOR'd; dest linear (rule #21)
      GLDS16(A  + (arow0 + row) * K + kt + gch, &As[c * 8]);
      GLDS16(Bt + (brow0 + row) * K + kt + gch, &Bs[c * 8]);
    }
    asm volatile("s_waitcnt vmcnt(0)" ::: "memory");
    __syncthreads();
    {
      bf16x8 a[4], b[4];
      #pragma unroll
      for (int i = 0; i < 4; ++i) {
        a[i] = *(const bf16x8*)&As[(wm + i * 16 + fr) * 64 + cr0];
        b[i] = *(const bf16x8*)&Bs[(wn + i * 16 + fr) * 64 + cr0];
      }
      #pragma unroll
      for (int i = 0; i < 4; ++i)
        #pragma unroll
        for (int j = 0; j < 4; ++j)
          acc[i][j] = MFMA16(a[i], b[j], acc[i][j]);
      #pragma unroll
      for (int i = 0; i < 4; ++i) {
        a[i] = *(const bf16x8*)&As[(wm + i * 16 + fr) * 64 + cr1];
        b[i] = *(const bf16x8*)&Bs[(wn + i * 16 + fr) * 64 + cr1];
      }
      #pragma unroll
      for (int i = 0; i < 4; ++i)
        #pragma unroll
        for (int j = 0; j < 4; ++j)
          acc[i][j] = MFMA16(a[i], b[j], acc[i][j]);
    }
    __syncthreads();
  }

  const int rq = q4 * 4;

  if (MODE == 3 && brow0 < 1024) {
    // fused q-softmax: each row's 64 head-cols live in lanes fr=0..15 (q4 fixed) x 4 j-regs
    float bv[4];
    #pragma unroll
    for (int j = 0; j < 4; ++j) bv[j] = bias[brow0 + wn + j * 16 + fr];
    #pragma unroll
    for (int i = 0; i < 4; ++i) {
      #pragma unroll
      for (int r = 0; r < 4; ++r) {
        float v[4];
        #pragma unroll
        for (int j = 0; j < 4; ++j) v[j] = acc[i][j][r] + bv[j];
        float m = fmaxf(fmaxf(v[0], v[1]), fmaxf(v[2], v[3]));
        #pragma unroll
        for (int o = 1; o <= 8; o <<= 1) m = fmaxf(m, __shfl_xor(m, o));
        float e[4], s = 0.f;
        #pragma unroll
        for (int j = 0; j < 4; ++j) { e[j] = __expf(v[j] - m); s += e[j]; }
        #pragma unroll
        for (int o = 1; o <= 8; o <<= 1) s += __shfl_xor(s, o);
        float inv = 1.0f / s;
        long row = arow0 + wm + i * 16 + rq + r;
        #pragma unroll
        for (int j = 0; j < 4; ++j)
          ((bf16_t*)outp)[row * N + brow0 + wn + j * 16 + fr] = (bf16_t)(e[j] * inv);
      }
    }
  } else {
    #pragma unroll
    for (int i = 0; i < 4; ++i) {
      #pragma unroll
      for (int j = 0; j < 4; ++j) {
        long col = brow0 + wn + j * 16 + fr;
        float bv = bias[col];
        #pragma unroll
        for (int r = 0; r < 4; ++r) {
          long row = arow0 + wm + i * 16 + rq + r;
          float v = acc[i][j][r] + bv;
          if (MODE == 0 || MODE == 3) {
            ((bf16_t*)outp)[row * N + col] = (bf16_t)v;
          } else if (MODE == 1) {
            ((float*)outp)[row * N + col] = v + resid[row * N + col];
          } else {
            float g = 0.5f * v * (1.0f + fast_erf(v * 0.70710678118654752f));
            ((bf16_t*)outp)[row * N + col] = (bf16_t)g;
          }
        }
      }
    }
  }
}

// ---------------------------------------------------------------- kv partials WITH fused exp + column-sum.
// No max subtraction: k ~ N(0,1) (LN-normalized input @ scaled weights), |k| <~ 6.5 -> exp safe in f32.
// kvp[(bh*8+ch)*4096 + d*64 + e] = sum_s exp(k[s,d]) v[s,e]   (unnormalized)
// esump[(bh*8+ch)*64 + d]       = sum_s exp(k[s,d])
__global__ __launch_bounds__(256) void kv_partial(const bf16_t* __restrict__ qkv,
                                                  float* __restrict__ kvp,
                                                  float* __restrict__ esump) {
  int bh = blockIdx.x, ch = blockIdx.y;
  int b = bh >> 4, h = bh & 15;
  int t = threadIdx.x;
  __shared__ float  Kexp[64][65];
  __shared__ bf16_t Vs[64][72];
  int rowl = t >> 2, c0 = (t & 3) * 16;
  int dd = t >> 2, e0 = (t & 3) * 16;
  int lsq = (t & 3) * 16;               // this thread's esum ls-quarter
  float acc[16] = {};
  float esum = 0.f;
  for (int sb = 0; sb < 8; ++sb) {
    long s = (long)ch * 512 + sb * 64 + rowl;
    const bf16_t* base = qkv + ((long)b * SS + s) * 3072 + h * 64;
    bf16x8 k0 = *(const bf16x8*)(base + 1024 + c0);
    bf16x8 k1 = *(const bf16x8*)(base + 1024 + c0 + 8);
    bf16x8 v0 = *(const bf16x8*)(base + 2048 + c0);
    bf16x8 v1 = *(const bf16x8*)(base + 2048 + c0 + 8);
    __syncthreads();
    #pragma unroll
    for (int j = 0; j < 8; ++j) {
      Kexp[rowl][c0 + j]     = __expf((float)k0[j]);
      Kexp[rowl][c0 + 8 + j] = __expf((float)k1[j]);
    }
    *(bf16x8*)&Vs[rowl][c0]     = v0;
    *(bf16x8*)&Vs[rowl][c0 + 8] = v1;
    __syncthreads();
    for (int ls = 0; ls < 64; ++ls) {
      float kd = Kexp[ls][dd];
      bf16x8 va = *(const bf16x8*)&Vs[ls][e0];
      bf16x8 vb = *(const bf16x8*)&Vs[ls][e0 + 8];
      #pragma unroll
      for (int j = 0; j < 8; ++j) {
        acc[j]     += kd * (float)va[j];
        acc[j + 8] += kd * (float)vb[j];
      }
    }
    #pragma unroll
    for (int l2 = 0; l2 < 16; ++l2) esum += Kexp[lsq + l2][dd];
  }
  float* dst = kvp + (long)(bh * 8 + ch) * 4096 + dd * 64 + e0;
  #pragma unroll
  for (int j = 0; j < 16; ++j) dst[j] = acc[j];
  // fold the 4 quarter-partials (threads dd*4 .. dd*4+3, consecutive lanes)
  esum += __shfl_xor(esum, 1);
  esum += __shfl_xor(esum, 2);
  if ((t & 3) == 0) esump[(long)(bh * 8 + ch) * 64 + dd] = esum;
}

// reduce partials + normalize, store TRANSPOSED bf16: kvT[bh][e][d]
__global__ void kv_reduce(const float* __restrict__ kvp, const float* __restrict__ esump,
                          bf16_t* __restrict__ kvT) {
  int bh = blockIdx.x, t = threadIdx.x;
  __shared__ float ei[64];
  if (t < 64) {
    float es = 0.f;
    #pragma unroll
    for (int c = 0; c < 8; ++c) es += esump[(long)(bh * 8 + c) * 64 + t];
    ei[t] = 1.0f / es;
  }
  __syncthreads();
  for (int p = t; p < 4096; p += 256) {
    int d = p >> 6, e = p & 63;
    float s = 0.f;
    #pragma unroll
    for (int c = 0; c < 8; ++c) s += kvp[(long)(bh * 8 + c) * 4096 + p];
    kvT[(long)bh * 4096 + e * 64 + d] = (bf16_t)(s * ei[d]);
  }
}

// ---------------------------------------------------------------- out[s,e] = q_sm[s,:] @ kv[:,e]  via MFMA, per (b,h)
__global__ __launch_bounds__(256) void attn_apply(const bf16_t* __restrict__ qkv,
                                                  const bf16_t* __restrict__ kvT,
                                                  bf16_t* __restrict__ attn) {
  int bh = blockIdx.x, sc = blockIdx.y;
  int b = bh >> 4, h = bh & 15;
  int t = threadIdx.x, lane = t & 63, w = t >> 6;
  __shared__ bf16_t kvs[64 * 64];
  for (int i = t * 8; i < 4096; i += 256 * 8)
    *(bf16x8*)&kvs[i] = *(const bf16x8*)(kvT + (long)bh * 4096 + i);
  __syncthreads();
  int fr = lane & 15, kq = (lane >> 4) * 8;
  long qrow = (long)b * SS + sc * 128 + w * 32;
  f32x4 acc[2][4] = {};
  #pragma unroll
  for (int kk = 0; kk < 2; ++kk) {
    bf16x8 a0 = *(const bf16x8*)(qkv + (qrow + fr) * 3072      + h * 64 + kk * 32 + kq);
    bf16x8 a1 = *(const bf16x8*)(qkv + (qrow + 16 + fr) * 3072 + h * 64 + kk * 32 + kq);
    #pragma unroll
    for (int j = 0; j < 4; ++j) {
      bf16x8 bfr = *(const bf16x8*)&kvs[(j * 16 + fr) * 64 + kk * 32 + kq];
      acc[0][j] = MFMA16(a0, bfr, acc[0][j]);
      acc[1][j] = MFMA16(a1, bfr, acc[1][j]);
    }
  }
  int rq = (lane >> 4) * 4;
  #pragma unroll
  for (int i = 0; i < 2; ++i)
    #pragma unroll
    for (int j = 0; j < 4; ++j)
      #pragma unroll
      for (int r = 0; r < 4; ++r)
        attn[(qrow + i * 16 + rq + r) * 1024 + h * 64 + j * 16 + fr] = (bf16_t)acc[i][j][r];
}

// ---------------------------------------------------------------- launch
extern "C" void kernel_launch(void* const* d_in, const int* in_sizes, int n_in,
                              void* d_out, int out_size, void* d_ws, size_t ws_size,
                              hipStream_t stream) {
  (void)in_sizes; (void)n_in; (void)out_size;
  const float* x      = (const float*)d_in[0];
  const float* w_qkv  = (const float*)d_in[1];
  const float* b_qkv  = (const float*)d_in[2];
  const float* w_out  = (const float*)d_in[3];
  const float* b_out  = (const float*)d_in[4];
  const float* w_ffn1 = (const float*)d_in[5];
  const float* b_ffn1 = (const float*)d_in[6];
  const float* w_ffn2 = (const float*)d_in[7];
  const float* b_ffn2 = (const float*)d_in[8];
  const float* g1     = (const float*)d_in[9];
  const float* be1    = (const float*)d_in[10];
  const float* g2     = (const float*)d_in[11];
  const float* be2    = (const float*)d_in[12];

  char* ws = (char*)d_ws;
  constexpr size_t WT_QKV_OFF  = 0;
  constexpr size_t WT_OUT_OFF  = WT_QKV_OFF  + 6291456;
  constexpr size_t WT_FFN1_OFF = WT_OUT_OFF  + 2097152;
  constexpr size_t WT_FFN2_OFF = WT_FFN1_OFF + 8388608;
  constexpr size_t ESUMP_OFF   = WT_FFN2_OFF + 8388608;   // 512*64*4 = 131072
  constexpr size_t KVP_OFF     = ESUMP_OFF   + 294912;    // keep alignment cushion
  constexpr size_t KVT_OFF     = KVP_OFF     + 8388608;
  constexpr size_t ACT1_OFF    = KVT_OFF     + 524288;
  constexpr size_t BIG_OFF     = ACT1_OFF    + 33554432;  // 67,928,064

  bf16_t* WT_QKV  = (bf16_t*)(ws + WT_QKV_OFF);
  bf16_t* WT_OUT  = (bf16_t*)(ws + WT_OUT_OFF);
  bf16_t* WT_FFN1 = (bf16_t*)(ws + WT_FFN1_OFF);
  bf16_t* WT_FFN2 = (bf16_t*)(ws + WT_FFN2_OFF);
  float*  ESUMP   = (float*) (ws + ESUMP_OFF);
  float*  KVP     = (float*) (ws + KVP_OFF);
  bf16_t* KVT     = (bf16_t*)(ws + KVT_OFF);
  bf16_t* ACT1    = (bf16_t*)(ws + ACT1_OFF);
  bf16_t* QKV     = (bf16_t*)(ws + BIG_OFF);   // 96 MB
  bf16_t* GACT    = (bf16_t*)(ws + BIG_OFF);   // up to 128 MB, after QKV dead
  float*  Y       = (float*)  d_out;           // residual mid-buffer lives in d_out

  const bool big_ws = ws_size >= (size_t)(BIG_OFF + 134217728ull);

  wtrans<<<dim3(3072 / 32, 1024 / 32), dim3(32, 8), 0, stream>>>(w_qkv,  WT_QKV,  1024, 3072);
  wtrans<<<dim3(1024 / 32, 1024 / 32), dim3(32, 8), 0, stream>>>(w_out,  WT_OUT,  1024, 1024);
  wtrans<<<dim3(4096 / 32, 1024 / 32), dim3(32, 8), 0, stream>>>(w_ffn1, WT_FFN1, 1024, 4096);
  wtrans<<<dim3(1024 / 32, 4096 / 32), dim3(32, 8), 0, stream>>>(w_ffn2, WT_FFN2, 4096, 1024);

  ln_kernel<<<NROWS, 256, 0, stream>>>(x, g1, be1, ACT1);

  // qkv = ln1 @ WqkvT + b, q-softmax fused in epilogue (grid 24 x 128)
  gemm_bt<3><<<dim3(3072 / 128, NROWS / 128), 256, 0, stream>>>(ACT1, WT_QKV, b_qkv, nullptr, QKV, NROWS, 3072, 1024);

  // kv einsum with fused exp + column-sum (no separate stats pass)
  kv_partial<<<dim3(64, 8), 256, 0, stream>>>(QKV, KVP, ESUMP);
  kv_reduce<<<64, 256, 0, stream>>>(KVP, ESUMP, KVT);
  attn_apply<<<dim3(64, SS / 128), 256, 0, stream>>>(QKV, KVT, ACT1);

  // y = x + attn_cat @ WoutT + b  -> d_out  (grid 8 x 128)
  gemm_bt<1><<<dim3(1024 / 128, NROWS / 128), 256, 0, stream>>>(ACT1, WT_OUT, b_out, x, Y, NROWS, 1024, 1024);

  ln_kernel<<<NROWS, 256, 0, stream>>>(Y, g2, be2, ACT1);

  if (big_ws) {
    // full-width FFN: ffn1 grid 32 x 128, ffn2 grid 8 x 128
    gemm_bt<2><<<dim3(4096 / 128, NROWS / 128), 256, 0, stream>>>(ACT1, WT_FFN1, b_ffn1, nullptr, GACT, NROWS, 4096, 1024);
    gemm_bt<1><<<dim3(1024 / 128, NROWS / 128), 256, 0, stream>>>(GACT, WT_FFN2, b_ffn2, x, (float*)d_out, NROWS, 1024, 4096);
  } else {
    for (int c = 0; c < 2; ++c) {
      const long r0 = (long)c * 8192;
      gemm_bt<2><<<dim3(4096 / 128, 8192 / 128), 256, 0, stream>>>(
          ACT1 + r0 * 1024, WT_FFN1, b_ffn1, nullptr, GACT, 8192, 4096, 1024);
      gemm_bt<1><<<dim3(1024 / 128, 8192 / 128), 256, 0, stream>>>(
          GACT, WT_FFN2, b_ffn2, x + r0 * 1024, (float*)d_out + r0 * 1024, 8192, 1024, 4096);
    }
  }
}